// Round 7
// baseline (44523.523 us; speedup 1.0000x reference)
//
#include <hip/hip_runtime.h>
#include <cstdint>

// ---------------------------------------------------------------------------
// RNNres: emb -> LSTM(T=2048,B=64,NHID=256) -> ragged mean pool -> ResNet head
//   k0 : convert emb_w / W_ih to f16, bias = b_ih + b_hh
//   k1 : MFMA f16 GEMM gate table; PERMUTED store xgtab[v*1024 + 4*u + g]
//   k2 : v7 — 4 WGs per batch element (grid 256 = all CUs, 256 thr/WG).
//        WG (b,q) owns units q*64..q*64+63, ALL 4 gates = 256 W_hh rows
//        = 128KB f16, ENTIRELY LDS-RESIDENT. This kills the invariant that
//        doomed v0-v6: FETCH_SIZE ~140GB = full W_hh re-fetched per step
//        (compiler remats read-only global loads instead of spilling; no
//        single CU can hold 512KB of weights). Per-step h-exchange between
//        the 4 WGs via global hglob + device-scope seq flags (release/
//        acquire, threadfence; all 256 WGs co-resident so spin is safe).
//        Thread owns one row (g=tid&3,u=tid>>2): gates of a unit live in
//        adjacent lanes -> shfl exchange. xg gather coalesced (512B/WG).
//   k3 : tiny fp32 head
// ---------------------------------------------------------------------------

#define NTOKEN 50257
#define NINP 256
#define NHID 256
#define BB 64
#define TT 2048
#define NRES 10
#define NFC1 85
#define EPSV 1e-5f

typedef _Float16 f16;
typedef _Float16 f16x2 __attribute__((ext_vector_type(2)));
typedef _Float16 f16x8 __attribute__((ext_vector_type(8)));
typedef float f32x4 __attribute__((ext_vector_type(4)));

static __device__ __forceinline__ float sigm(float x) { return 1.0f / (1.0f + __expf(-x)); }
static __device__ __forceinline__ float tanh_(float x) {
  float ax = fabsf(x);
  float e = __expf(-2.0f * ax);
  float t = (1.0f - e) / (1.0f + e);
  return x < 0.0f ? -t : t;
}

static __device__ __forceinline__ float fdot2(f16x2 a, f16x2 b, float c) {
#if __has_builtin(__builtin_amdgcn_fdot2)
  return __builtin_amdgcn_fdot2(a, b, c, false);
#else
  return c + (float)a[0] * (float)b[0] + (float)a[1] * (float)b[1];
#endif
}
static __device__ __forceinline__ f16x2 bch(unsigned int u) {
  return __builtin_bit_cast(f16x2, u);
}

// ---------------------------------------------------------------- k0: convert
__global__ void k0_convert(const float* __restrict__ emb_w, const float* __restrict__ W_ih,
                           const float* __restrict__ b_ih, const float* __restrict__ b_hh,
                           f16* __restrict__ emb16, f16* __restrict__ wih16,
                           float* __restrict__ bias) {
  int64_t i = (int64_t)blockIdx.x * blockDim.x + threadIdx.x;
  if (i < (int64_t)NTOKEN * NINP) emb16[i] = (f16)emb_w[i];
  if (i < 4 * NHID * NINP) wih16[i] = (f16)W_ih[i];
  if (i < 4 * NHID) bias[i] = b_ih[i] + b_hh[i];
}

// ------------------------------------------------- k1: gate-table f16 GEMM
__global__ __launch_bounds__(256) void k1_gemm(const f16* __restrict__ emb16,
                                               const f16* __restrict__ wih16,
                                               const float* __restrict__ bias,
                                               f16* __restrict__ xgtab) {
  __shared__ __align__(16) f16 a_lds[64][40];
  __shared__ __align__(16) f16 b_lds[256][40];
  const int mt = blockIdx.x;
  const int nt0 = blockIdx.y * 256;
  const int tid = threadIdx.x;
  const int lane = tid & 63;
  const int w = tid >> 6;
  const int quad = lane >> 4;
  const int l16 = lane & 15;

  f32x4 acc[16];
#pragma unroll
  for (int i = 0; i < 16; i++) acc[i] = (f32x4){0.f, 0.f, 0.f, 0.f};

  const int ar = tid >> 2;
  int av = mt * 64 + ar;
  if (av > NTOKEN - 1) av = NTOKEN - 1;
  const int ac = (tid & 3) * 8;

  for (int kb = 0; kb < 256; kb += 32) {
    *(uint4*)&a_lds[ar][ac] = *(const uint4*)&emb16[av * 256 + kb + ac];
    {
      const uint4* bs = (const uint4*)&wih16[(nt0 + tid) * 256 + kb];
      uint4* bd = (uint4*)&b_lds[tid][0];
      bd[0] = bs[0]; bd[1] = bs[1]; bd[2] = bs[2]; bd[3] = bs[3];
    }
    __syncthreads();
    f16x8 af = *(const f16x8*)&a_lds[w * 16 + l16][quad * 8];
#pragma unroll
    for (int nt = 0; nt < 16; nt++) {
      f16x8 bf = *(const f16x8*)&b_lds[nt * 16 + l16][quad * 8];
      acc[nt] = __builtin_amdgcn_mfma_f32_16x16x32_f16(af, bf, acc[nt], 0, 0, 0);
    }
    __syncthreads();
  }
  // permuted store: unit u = nt*16 + l16 (+256-chunk), gate = blockIdx.y
  // -> idx = nt*64 + l16*4 + gate == 4*u + gate
#pragma unroll
  for (int nt = 0; nt < 16; nt++) {
#pragma unroll
    for (int rg = 0; rg < 4; rg++) {
      int v = mt * 64 + w * 16 + quad * 4 + rg;
      if (v < NTOKEN) {
        int n = nt0 + nt * 16 + l16;
        xgtab[v * 1024 + nt * 64 + l16 * 4 + blockIdx.y] = (f16)(acc[nt][rg] + bias[n]);
      }
    }
  }
}

// ------------------------------------------------------- k2: LSTM recurrence
// grid 256: q = bid>>6 (unit group), b = bid&63 (batch). 256 threads:
// g = tid&3 (gate 0=i,1=f,2=cell,3=o), uu = tid>>2 (unit in group).
// Thread's W_hh row: g*256 + q*64 + uu  — resident in LDS (pitch-65 uint2,
// bank-conflict-free). Per step: dot over full h (LDS broadcast), shfl gate
// exchange, publish own 64 h to hglob, seq-flag sync, reload full h.
__global__ __launch_bounds__(256)
void k2_rnn(const int* __restrict__ input, const float* __restrict__ hx0,
            const float* __restrict__ cx0, const int* __restrict__ seq_len,
            const float* __restrict__ Whh, const f16* __restrict__ xgtab,
            f16* __restrict__ hglob, unsigned int* __restrict__ seq,
            float* __restrict__ feat, float* __restrict__ out_hx,
            float* __restrict__ out_cx) {
  __shared__ uint2 wl2[256 * 65];                // 133,120 B (pitch 65 kills conflicts)
  __shared__ __align__(16) f16 hstage[2][NHID];  // 1,024 B double-buffered full h

  const int bid = blockIdx.x;
  const int q = bid >> 6;          // unit group 0..3
  const int b = bid & 63;          // batch element; partners b,b+64,b+128,b+192 same XCD
  const int tid = threadIdx.x;
  const int wid = tid >> 6;
  const int lane = tid & 63;
  const int g = tid & 3;
  const int uu = tid >> 2;
  const int U = q * 64 + uu;       // global unit id this lane owns (g==0 lanes)

  // ---- cooperative, coalesced weight load: wave wid loads LDS-row r's 1KB
  //      (LDS row r holds thread r's W_hh row: g_r = r&3, uu_r = r>>2)
  for (int r = wid; r < 256; r += 4) {
    const int grow = (r & 3) * 256 + q * 64 + (r >> 2);
    const float4 v = ((const float4*)(Whh + grow * 256))[lane];
    f16x2 p0; p0[0] = (f16)v.x; p0[1] = (f16)v.y;
    f16x2 p1; p1[0] = (f16)v.z; p1[1] = (f16)v.w;
    wl2[r * 65 + lane] = make_uint2(__builtin_bit_cast(unsigned int, p0),
                                    __builtin_bit_cast(unsigned int, p1));
  }

  // ---- init h0 / c0
  hstage[0][tid] = (f16)hx0[b * NHID + tid];
  float c = 0.f, pool = 0.f, hlast = 0.f;
  if (g == 0) c = cx0[b * NHID + U];
  const int L = seq_len[b];

  const int* tokp = input + b * TT;
  f16* hgb = hglob + b * 2 * NHID;                 // [2][256] per batch
  unsigned int* myseq = seq + (b * 4 + q) * 16;    // 64B-padded flags
  unsigned int* seqb = seq + (b * 4) * 16;

  int toknx = tokp[1];
  f16 xgc = xgtab[(int64_t)tokp[0] * 1024 + q * 256 + tid];
  __syncthreads();

#pragma unroll 1
  for (int t = 0; t < TT; ++t) {
    const int cur = t & 1;
    const int nxt = cur ^ 1;

    // prefetch next-step xg (coalesced 512B/WG) + token
    f16 xgn = xgtab[(int64_t)toknx * 1024 + q * 256 + tid];
    const int tok2 = tokp[(t + 2 < TT) ? (t + 2) : (TT - 1)];

    // ---- dot: 128 half2 pairs from LDS (2-lane/bank = free), h broadcast b128
    float a0 = (float)xgc, a1 = 0.f, a2 = 0.f, a3 = 0.f;
    const uint2* wrow = wl2 + tid * 65;
    const uint4* hp = (const uint4*)&hstage[cur][0];
#pragma unroll
    for (int k = 0; k < 32; ++k) {
      const uint4 hq = hp[k];
      const uint2 wa = wrow[2 * k];
      const uint2 wb = wrow[2 * k + 1];
      a0 = fdot2(bch(wa.x), bch(hq.x), a0);
      a1 = fdot2(bch(wa.y), bch(hq.y), a1);
      a2 = fdot2(bch(wb.x), bch(hq.z), a2);
      a3 = fdot2(bch(wb.y), bch(hq.w), a3);
    }
    const float acc = (a0 + a1) + (a2 + a3);

    // ---- per-gate activation, 4-adjacent-lane exchange
    const float sv = sigm(acc);
    const float act = (g == 2) ? tanh_(acc) : sv;
    const float fch = __shfl_down(act, 1);
    const float gch = __shfl_down(act, 2);
    const float och = __shfl_down(act, 3);
    float hv = 0.f;
    if (g == 0) {
      c = fch * c + act * gch;
      hv = och * tanh_(c);
      hlast = hv;
      if (t < L) pool += hv;
    }

    if (t != TT - 1) {
      // ---- publish own 64 h values (128B) to this batch's next buffer
      if (g == 0) hgb[nxt * NHID + U] = (f16)hv;
      __threadfence();                       // flush to device scope (cross-XCD safe)
      __syncthreads();                       // all waves' stores drained + fenced
      if (tid == 0)
        __hip_atomic_store(myseq, (unsigned int)(t + 1),
                           __ATOMIC_RELEASE, __HIP_MEMORY_SCOPE_AGENT);
      // ---- wait for all 4 groups, then reload the full 512B h
      if (tid < 4) {
        const unsigned int* sp = seqb + tid * 16;
        while (__hip_atomic_load(sp, __ATOMIC_ACQUIRE, __HIP_MEMORY_SCOPE_AGENT) <
               (unsigned int)(t + 1))
          __builtin_amdgcn_s_sleep(1);
      }
      if (tid < 32) {
        const uint4 v = ((const uint4*)(hgb + nxt * NHID))[tid];
        ((uint4*)&hstage[nxt][0])[tid] = v;
      }
      __syncthreads();
    }
    xgc = xgn;
    toknx = tok2;
  }

  if (g == 0) {
    feat[b * NHID + U] = pool / (float)L;
    out_hx[b * NHID + U] = hlast;
    out_cx[b * NHID + U] = c;
  }
}

// ------------------------------------------------------------- k3: head (fp32)
__global__ __launch_bounds__(256) void k3_head(const float* __restrict__ feat,
    const float* __restrict__ rfc1_w, const float* __restrict__ rfc1_b,
    const float* __restrict__ rbn_g, const float* __restrict__ rbn_b,
    const float* __restrict__ rbn_rm, const float* __restrict__ rbn_rv,
    const float* __restrict__ rfc2_w, const float* __restrict__ rfc2_b,
    const float* __restrict__ fc1_w, const float* __restrict__ fc1_b,
    const float* __restrict__ bn1_g, const float* __restrict__ bn1_b,
    const float* __restrict__ bn1_rm, const float* __restrict__ bn1_rv,
    const float* __restrict__ fc2_w, const float* __restrict__ fc2_b,
    float* __restrict__ logp) {
  __shared__ float f[256];
  __shared__ float f2[256];
  __shared__ float res[16];
  __shared__ float fcv[96];
  const int b = blockIdx.x, tid = threadIdx.x;
  const int wv = tid >> 6, lane = tid & 63;
  f[tid] = feat[b * 256 + tid];
  __syncthreads();
  for (int r = wv; r < NRES; r += 4) {
    float p = 0.f;
#pragma unroll
    for (int j0 = 0; j0 < 4; j0++) {
      int j = lane * 4 + j0;
      p += fmaxf(f[j], 0.f) * rfc1_w[r * 256 + j];
    }
    for (int off = 32; off > 0; off >>= 1) p += __shfl_down(p, off);
    if (lane == 0) {
      float x = p + rfc1_b[r];
      x = fmaxf(x, 0.f);
      x = (x - rbn_rm[r]) * rsqrtf(rbn_rv[r] + EPSV) * rbn_g[r] + rbn_b[r];
      res[r] = x;
    }
  }
  __syncthreads();
  {
    float s = rfc2_b[tid];
#pragma unroll
    for (int r = 0; r < NRES; r++) s += res[r] * rfc2_w[tid * NRES + r];
    f2[tid] = f[tid] + s;
  }
  __syncthreads();
  for (int o = wv; o < NFC1; o += 4) {
    float p = 0.f;
#pragma unroll
    for (int j0 = 0; j0 < 4; j0++) {
      int j = lane * 4 + j0;
      p += f2[j] * fc1_w[o * 256 + j];
    }
    for (int off = 32; off > 0; off >>= 1) p += __shfl_down(p, off);
    if (lane == 0) {
      float x = p + fc1_b[o];
      x = (x - bn1_rm[o]) * rsqrtf(bn1_rv[o] + EPSV) * bn1_g[o] + bn1_b[o];
      x = fmaxf(x, 0.01f * x);
      fcv[o] = x;
    }
  }
  __syncthreads();
  if (tid == 0) {
    float l0 = fc2_b[0], l1 = fc2_b[1];
    for (int o2 = 0; o2 < NFC1; o2++) {
      l0 += fcv[o2] * fc2_w[o2];
      l1 += fcv[o2] * fc2_w[NFC1 + o2];
    }
    float mx = fmaxf(l0, l1);
    float lse = mx + __logf(__expf(l0 - mx) + __expf(l1 - mx));
    logp[b * 2 + 0] = l0 - lse;
    logp[b * 2 + 1] = l1 - lse;
  }
}

// ---------------------------------------------------------------------------
extern "C" void kernel_launch(void* const* d_in, const int* in_sizes, int n_in,
                              void* d_out, int out_size, void* d_ws, size_t ws_size,
                              hipStream_t stream) {
  const int*   input  = (const int*)  d_in[0];
  const float* hx     = (const float*)d_in[1];
  const float* cx     = (const float*)d_in[2];
  const int*   seqlen = (const int*)  d_in[3];
  const float* emb_w  = (const float*)d_in[4];
  const float* W_ih   = (const float*)d_in[5];
  const float* W_hh   = (const float*)d_in[6];
  const float* b_ih   = (const float*)d_in[7];
  const float* b_hh   = (const float*)d_in[8];
  const float* rfc1_w = (const float*)d_in[9];
  const float* rfc1_b = (const float*)d_in[10];
  const float* rbn_g  = (const float*)d_in[11];
  const float* rbn_b  = (const float*)d_in[12];
  const float* rbn_rm = (const float*)d_in[13];
  const float* rbn_rv = (const float*)d_in[14];
  const float* rfc2_w = (const float*)d_in[15];
  const float* rfc2_b = (const float*)d_in[16];
  const float* fc1_w  = (const float*)d_in[17];
  const float* fc1_b  = (const float*)d_in[18];
  const float* bn1_g  = (const float*)d_in[19];
  const float* bn1_b  = (const float*)d_in[20];
  const float* bn1_rm = (const float*)d_in[21];
  const float* bn1_rv = (const float*)d_in[22];
  const float* fc2_w  = (const float*)d_in[23];
  const float* fc2_b  = (const float*)d_in[24];

  char* ws = (char*)d_ws;
  f16*   emb16 = (f16*)(ws);                 // 25,731,584 B (dead after k1)
  f16*   wih16 = (f16*)(ws + 25731584);      //    524,288 B
  float* bias  = (float*)(ws + 26255872);    //      4,096 B
  f16*   xgtab = (f16*)(ws + 26259968);      // 102,926,336 B
  float* feat  = (float*)(ws + 129186304);   //     65,536 B
  // h-exchange buffers carved from the DEAD emb16 region (k2 runs after k1)
  f16*          hglob = (f16*)(ws + 24 * 1024 * 1024);           // 65,536 B
  unsigned int* seqf  = (unsigned int*)(ws + 24 * 1024 * 1024 + 65536);  // 16,384 B

  float* out = (float*)d_out;   // [0,128): logp, [128,16512): hx_f, [16512,32896): cx_f

  k0_convert<<<dim3(NTOKEN), 256, 0, stream>>>(emb_w, W_ih, b_ih, b_hh, emb16, wih16, bias);
  k1_gemm<<<dim3((NTOKEN + 63) / 64, 4), 256, 0, stream>>>(emb16, wih16, bias, xgtab);
  hipMemsetAsync(seqf, 0, 64 * 4 * 16 * sizeof(unsigned int), stream);
  k2_rnn<<<dim3(4 * BB), 256, 0, stream>>>(input, hx, cx, seqlen, W_hh, xgtab,
                                           hglob, seqf, feat,
                                           out + 128, out + 128 + BB * NHID);
  k3_head<<<dim3(BB), 256, 0, stream>>>(feat, rfc1_w, rfc1_b, rbn_g, rbn_b, rbn_rm, rbn_rv,
                                        rfc2_w, rfc2_b, fc1_w, fc1_b, bn1_g, bn1_b, bn1_rm,
                                        bn1_rv, fc2_w, fc2_b, out);
}

// Round 8
// 4790.368 us; speedup vs baseline: 9.2944x; 9.2944x over previous
//
#include <hip/hip_runtime.h>
#include <cstdint>

// ---------------------------------------------------------------------------
// RNNres: emb -> LSTM(T=2048,B=64,NHID=256) -> ragged mean pool -> ResNet head
//   k0 : convert emb_w / W_ih to f16, bias = b_ih + b_hh
//   k1 : MFMA f16 GEMM gate table; PERMUTED store xgtab[v*1024 + 4*u + g]
//   k0b: convert W_hh to f16
//   k2 : v8 = v3/v4 MFMA recurrence with FULL weight residency.
//        Root cause of v0-v6 (FETCH ~141GB): compiler REMATERIALIZES
//        read-only global weight loads instead of keeping them in regs
//        (VGPR_Count stuck at 64-128). Fix: opaque-asm pin
//        (asm volatile("" : "+v"(frag))) -> uses cannot be remat'd.
//        64 frags/wave: 45 VGPR-pinned (180 regs) + 19 LDS (152KB). ZERO
//        per-step global weight traffic. v7's cross-WG global sync (44ms)
//        is gone: back to 1 WG/batch, one barrier/step.
//   k3 : tiny fp32 head
// ---------------------------------------------------------------------------

#define NTOKEN 50257
#define NINP 256
#define NHID 256
#define BB 64
#define TT 2048
#define NRES 10
#define NFC1 85
#define EPSV 1e-5f

#define NREGF 45   // frags f < NREGF in VGPRs (asm-pinned)
#define NLDSF 19   // frags NREGF <= f < 64 in LDS

typedef _Float16 f16;
typedef _Float16 f16x2 __attribute__((ext_vector_type(2)));
typedef _Float16 f16x4 __attribute__((ext_vector_type(4)));
typedef _Float16 f16x8 __attribute__((ext_vector_type(8)));
typedef float f32x4 __attribute__((ext_vector_type(4)));

static __device__ __forceinline__ float sigm(float x) { return 1.0f / (1.0f + __expf(-x)); }
static __device__ __forceinline__ float tanh_(float x) {
  float ax = fabsf(x);
  float e = __expf(-2.0f * ax);
  float t = (1.0f - e) / (1.0f + e);
  return x < 0.0f ? -t : t;
}

// ---------------------------------------------------------------- k0: convert
__global__ void k0_convert(const float* __restrict__ emb_w, const float* __restrict__ W_ih,
                           const float* __restrict__ b_ih, const float* __restrict__ b_hh,
                           f16* __restrict__ emb16, f16* __restrict__ wih16,
                           float* __restrict__ bias) {
  int64_t i = (int64_t)blockIdx.x * blockDim.x + threadIdx.x;
  if (i < (int64_t)NTOKEN * NINP) emb16[i] = (f16)emb_w[i];
  if (i < 4 * NHID * NINP) wih16[i] = (f16)W_ih[i];
  if (i < 4 * NHID) bias[i] = b_ih[i] + b_hh[i];
}

// ---------------------------------------------- k0b: W_hh -> f16 (after k1!)
__global__ void k0b_whh(const float* __restrict__ Whh, f16* __restrict__ whh16) {
  int i = blockIdx.x * 256 + threadIdx.x;
  if (i < 4 * NHID * NHID) whh16[i] = (f16)Whh[i];
}

// ------------------------------------------------- k1: gate-table f16 GEMM
__global__ __launch_bounds__(256) void k1_gemm(const f16* __restrict__ emb16,
                                               const f16* __restrict__ wih16,
                                               const float* __restrict__ bias,
                                               f16* __restrict__ xgtab) {
  __shared__ __align__(16) f16 a_lds[64][40];
  __shared__ __align__(16) f16 b_lds[256][40];
  const int mt = blockIdx.x;
  const int nt0 = blockIdx.y * 256;
  const int tid = threadIdx.x;
  const int lane = tid & 63;
  const int w = tid >> 6;
  const int quad = lane >> 4;
  const int l16 = lane & 15;

  f32x4 acc[16];
#pragma unroll
  for (int i = 0; i < 16; i++) acc[i] = (f32x4){0.f, 0.f, 0.f, 0.f};

  const int ar = tid >> 2;
  int av = mt * 64 + ar;
  if (av > NTOKEN - 1) av = NTOKEN - 1;
  const int ac = (tid & 3) * 8;

  for (int kb = 0; kb < 256; kb += 32) {
    *(uint4*)&a_lds[ar][ac] = *(const uint4*)&emb16[av * 256 + kb + ac];
    {
      const uint4* bs = (const uint4*)&wih16[(nt0 + tid) * 256 + kb];
      uint4* bd = (uint4*)&b_lds[tid][0];
      bd[0] = bs[0]; bd[1] = bs[1]; bd[2] = bs[2]; bd[3] = bs[3];
    }
    __syncthreads();
    f16x8 af = *(const f16x8*)&a_lds[w * 16 + l16][quad * 8];
#pragma unroll
    for (int nt = 0; nt < 16; nt++) {
      f16x8 bf = *(const f16x8*)&b_lds[nt * 16 + l16][quad * 8];
      acc[nt] = __builtin_amdgcn_mfma_f32_16x16x32_f16(af, bf, acc[nt], 0, 0, 0);
    }
    __syncthreads();
  }
  // permuted store: n = nt0 + nt*16 + l16 -> idx = nt*64 + l16*4 + gate
  // (gate = blockIdx.y since nt0 = gate*256)
#pragma unroll
  for (int nt = 0; nt < 16; nt++) {
#pragma unroll
    for (int rg = 0; rg < 4; rg++) {
      int v = mt * 64 + w * 16 + quad * 4 + rg;
      if (v < NTOKEN) {
        int n = nt0 + nt * 16 + l16;
        xgtab[v * 1024 + nt * 64 + l16 * 4 + blockIdx.y] = (f16)(acc[nt][rg] + bias[n]);
      }
    }
  }
}

// ------------------------------------------------------- k2: MFMA recurrence
// Wave w owns N-rows {g*256 + w*32 + hh*16 + l16 : g in 0..3, hh in 0..1}
// (8 N-tiles, nt = g*2+hh). A operand: row 0 = h (lanes l16==0 carry it),
// rows 1-15 zero. C layout (harness-verified via k1/v3/v4): M-row=quad*4+reg,
// N-col=l16 -> valid outputs on quad==0 lanes, reg 0; all 4 gates of a
// hidden unit land in the SAME lane.
__global__ __attribute__((amdgpu_flat_work_group_size(512, 512), amdgpu_waves_per_eu(2, 2)))
void k2_rnn(const int* __restrict__ input, const float* __restrict__ hx0,
            const float* __restrict__ cx0, const int* __restrict__ seq_len,
            const f16* __restrict__ whh16, const f16* __restrict__ xgtab,
            float* __restrict__ feat, float* __restrict__ out_hx,
            float* __restrict__ out_cx) {
  __shared__ __align__(16) f16 wlds[8][NLDSF][64][8];  // 155,648 B
  __shared__ __align__(16) f16 hbuf[2][256];           // 1,024 B

  const int b = blockIdx.x;
  const int tid = threadIdx.x;
  const int w = tid >> 6;
  const int lane = tid & 63;
  const int quad = lane >> 4;
  const int l16 = lane & 15;

  // per-lane element offset within a W_hh row-block: row (w*32+l16), col quad*8
  const int goff = (w * 32 + l16) * 256 + quad * 8;

  // ---- load ALL weight frags (f = ks*8 + nt; nt = g*2+hh). f<NREGF to regs,
  //      rest to LDS. Register frags are then PINNED via opaque empty asm so
  //      the compiler cannot rematerialize their uses from the global loads.
  f16x8 wreg[NREGF];
#pragma unroll
  for (int ks = 0; ks < 8; ++ks) {
#pragma unroll
    for (int nt = 0; nt < 8; ++nt) {
      const int f = ks * 8 + nt;
      const int g = nt >> 1, hh = nt & 1;
      f16x8 fr = *(const f16x8*)(whh16 + (g * 256 + hh * 16) * 256 + ks * 32 + goff);
      if (f < NREGF) wreg[f] = fr;
      else *(f16x8*)&wlds[w][f - NREGF][lane][0] = fr;
    }
  }
#pragma unroll
  for (int f = 0; f < NREGF; ++f) {
    asm volatile("" : "+v"(wreg[f]));   // opaque pin: no remat of uses
  }

  float cst[2] = {0.f, 0.f}, pool2[2] = {0.f, 0.f}, hlast[2] = {0.f, 0.f};
  if (quad == 0) {
#pragma unroll
    for (int hh = 0; hh < 2; ++hh) {
      const int n = w * 32 + hh * 16 + l16;
      hbuf[0][n] = (f16)hx0[b * 256 + n];
      cst[hh] = cx0[b * 256 + n];
    }
  }
  const int L = seq_len[b];
  const int* tokp = input + b * TT;
  int tok_cur = tokp[0];
  __syncthreads();

#pragma unroll 1
  for (int t = 0; t < TT; ++t) {
    const int cur = t & 1;

    // ---- xg gather for THIS step (consumed post-MFMA => latency self-hides)
    uint2 xg0 = {0u, 0u}, xg1 = {0u, 0u};
    if (quad == 0) {
      const f16* xr = xgtab + (int64_t)tok_cur * 1024 + w * 128 + l16 * 4;
      xg0 = *(const uint2*)xr;
      xg1 = *(const uint2*)(xr + 64);
    }
    const int tok_nx = tokp[(t + 1 < TT) ? (t + 1) : (TT - 1)];

    // ---- MFMA sweep, acc starts at 0 (xg added in elementwise phase)
    f32x4 acc[8];
#pragma unroll
    for (int nt = 0; nt < 8; ++nt) acc[nt] = (f32x4){0.f, 0.f, 0.f, 0.f};

#pragma unroll
    for (int ks = 0; ks < 8; ++ks) {
      f16x8 af;
#pragma unroll
      for (int z = 0; z < 8; ++z) af[z] = (f16)0;
      if (l16 == 0) af = *(const f16x8*)&hbuf[cur][ks * 32 + quad * 8];
#pragma unroll
      for (int nt = 0; nt < 8; ++nt) {
        const int f = ks * 8 + nt;
        f16x8 bf;
        if (f < NREGF) bf = wreg[f];
        else bf = *(const f16x8*)&wlds[w][f - NREGF][lane][0];
        acc[nt] = __builtin_amdgcn_mfma_f32_16x16x32_f16(af, bf, acc[nt], 0, 0, 0);
      }
    }

    // ---- elementwise: all 4 gates of (n = w*32+hh*16+l16) live in this lane
    if (quad == 0) {
      const f16x4 xa = __builtin_bit_cast(f16x4, xg0);
      const f16x4 xb = __builtin_bit_cast(f16x4, xg1);
#pragma unroll
      for (int hh = 0; hh < 2; ++hh) {
        const f16x4 xv = hh ? xb : xa;
        const float iv = sigm(acc[0 + hh][0] + (float)xv[0]);
        const float fv = sigm(acc[2 + hh][0] + (float)xv[1]);
        const float gv = tanh_(acc[4 + hh][0] + (float)xv[2]);
        const float ov = sigm(acc[6 + hh][0] + (float)xv[3]);
        const float cc = fv * cst[hh] + iv * gv;
        cst[hh] = cc;
        const float hv = ov * tanh_(cc);
        hlast[hh] = hv;
        if (t < L) pool2[hh] += hv;
        hbuf[cur ^ 1][w * 32 + hh * 16 + l16] = (f16)hv;
      }
    }
    tok_cur = tok_nx;
    __syncthreads();
  }

  if (quad == 0) {
#pragma unroll
    for (int hh = 0; hh < 2; ++hh) {
      const int n = w * 32 + hh * 16 + l16;
      feat[b * 256 + n] = pool2[hh] / (float)L;
      out_hx[b * 256 + n] = hlast[hh];
      out_cx[b * 256 + n] = cst[hh];
    }
  }
}

// ------------------------------------------------------------- k3: head (fp32)
__global__ __launch_bounds__(256) void k3_head(const float* __restrict__ feat,
    const float* __restrict__ rfc1_w, const float* __restrict__ rfc1_b,
    const float* __restrict__ rbn_g, const float* __restrict__ rbn_b,
    const float* __restrict__ rbn_rm, const float* __restrict__ rbn_rv,
    const float* __restrict__ rfc2_w, const float* __restrict__ rfc2_b,
    const float* __restrict__ fc1_w, const float* __restrict__ fc1_b,
    const float* __restrict__ bn1_g, const float* __restrict__ bn1_b,
    const float* __restrict__ bn1_rm, const float* __restrict__ bn1_rv,
    const float* __restrict__ fc2_w, const float* __restrict__ fc2_b,
    float* __restrict__ logp) {
  __shared__ float f[256];
  __shared__ float f2[256];
  __shared__ float res[16];
  __shared__ float fcv[96];
  const int b = blockIdx.x, tid = threadIdx.x;
  const int wv = tid >> 6, lane = tid & 63;
  f[tid] = feat[b * 256 + tid];
  __syncthreads();
  for (int r = wv; r < NRES; r += 4) {
    float p = 0.f;
#pragma unroll
    for (int j0 = 0; j0 < 4; j0++) {
      int j = lane * 4 + j0;
      p += fmaxf(f[j], 0.f) * rfc1_w[r * 256 + j];
    }
    for (int off = 32; off > 0; off >>= 1) p += __shfl_down(p, off);
    if (lane == 0) {
      float x = p + rfc1_b[r];
      x = fmaxf(x, 0.f);
      x = (x - rbn_rm[r]) * rsqrtf(rbn_rv[r] + EPSV) * rbn_g[r] + rbn_b[r];
      res[r] = x;
    }
  }
  __syncthreads();
  {
    float s = rfc2_b[tid];
#pragma unroll
    for (int r = 0; r < NRES; r++) s += res[r] * rfc2_w[tid * NRES + r];
    f2[tid] = f[tid] + s;
  }
  __syncthreads();
  for (int o = wv; o < NFC1; o += 4) {
    float p = 0.f;
#pragma unroll
    for (int j0 = 0; j0 < 4; j0++) {
      int j = lane * 4 + j0;
      p += f2[j] * fc1_w[o * 256 + j];
    }
    for (int off = 32; off > 0; off >>= 1) p += __shfl_down(p, off);
    if (lane == 0) {
      float x = p + fc1_b[o];
      x = (x - bn1_rm[o]) * rsqrtf(bn1_rv[o] + EPSV) * bn1_g[o] + bn1_b[o];
      x = fmaxf(x, 0.01f * x);
      fcv[o] = x;
    }
  }
  __syncthreads();
  if (tid == 0) {
    float l0 = fc2_b[0], l1 = fc2_b[1];
    for (int o2 = 0; o2 < NFC1; o2++) {
      l0 += fcv[o2] * fc2_w[o2];
      l1 += fcv[o2] * fc2_w[NFC1 + o2];
    }
    float mx = fmaxf(l0, l1);
    float lse = mx + __logf(__expf(l0 - mx) + __expf(l1 - mx));
    logp[b * 2 + 0] = l0 - lse;
    logp[b * 2 + 1] = l1 - lse;
  }
}

// ---------------------------------------------------------------------------
extern "C" void kernel_launch(void* const* d_in, const int* in_sizes, int n_in,
                              void* d_out, int out_size, void* d_ws, size_t ws_size,
                              hipStream_t stream) {
  const int*   input  = (const int*)  d_in[0];
  const float* hx     = (const float*)d_in[1];
  const float* cx     = (const float*)d_in[2];
  const int*   seqlen = (const int*)  d_in[3];
  const float* emb_w  = (const float*)d_in[4];
  const float* W_ih   = (const float*)d_in[5];
  const float* W_hh   = (const float*)d_in[6];
  const float* b_ih   = (const float*)d_in[7];
  const float* b_hh   = (const float*)d_in[8];
  const float* rfc1_w = (const float*)d_in[9];
  const float* rfc1_b = (const float*)d_in[10];
  const float* rbn_g  = (const float*)d_in[11];
  const float* rbn_b  = (const float*)d_in[12];
  const float* rbn_rm = (const float*)d_in[13];
  const float* rbn_rv = (const float*)d_in[14];
  const float* rfc2_w = (const float*)d_in[15];
  const float* rfc2_b = (const float*)d_in[16];
  const float* fc1_w  = (const float*)d_in[17];
  const float* fc1_b  = (const float*)d_in[18];
  const float* bn1_g  = (const float*)d_in[19];
  const float* bn1_b  = (const float*)d_in[20];
  const float* bn1_rm = (const float*)d_in[21];
  const float* bn1_rv = (const float*)d_in[22];
  const float* fc2_w  = (const float*)d_in[23];
  const float* fc2_b  = (const float*)d_in[24];

  char* ws = (char*)d_ws;
  f16*   emb16 = (f16*)(ws);                 // 25,731,584 B (dead after k1)
  f16*   whh16 = (f16*)(ws);                 // 524,288 B, aliases emb16 (k0b after k1)
  f16*   wih16 = (f16*)(ws + 25731584);      //    524,288 B
  float* bias  = (float*)(ws + 26255872);    //      4,096 B
  f16*   xgtab = (f16*)(ws + 26259968);      // 102,926,336 B
  float* feat  = (float*)(ws + 129186304);   //     65,536 B

  float* out = (float*)d_out;   // [0,128): logp, [128,16512): hx_f, [16512,32896): cx_f

  k0_convert<<<dim3(NTOKEN), 256, 0, stream>>>(emb_w, W_ih, b_ih, b_hh, emb16, wih16, bias);
  k1_gemm<<<dim3((NTOKEN + 63) / 64, 4), 256, 0, stream>>>(emb16, wih16, bias, xgtab);
  k0b_whh<<<dim3((4 * NHID * NHID + 255) / 256), 256, 0, stream>>>(W_hh, whh16);
  k2_rnn<<<dim3(BB), 512, 0, stream>>>(input, hx, cx, seqlen, whh16, xgtab, feat,
                                       out + 128, out + 128 + BB * NHID);
  k3_head<<<dim3(BB), 256, 0, stream>>>(feat, rfc1_w, rfc1_b, rbn_g, rbn_b, rbn_rm, rbn_rv,
                                        rfc2_w, rfc2_b, fc1_w, fc1_b, bn1_g, bn1_b, bn1_rm,
                                        bn1_rv, fc2_w, fc2_b, out);
}